// Round 1
// baseline (160.136 us; speedup 1.0000x reference)
//
#include <hip/hip_runtime.h>
#include <math.h>

// YOLO box decode: (32, 3*85, 52, 52) -> (32*3*52*52, 85)
// R10: COPY-SHAPED READS. R9 established: 52-lane dwordx2 416 B runs plateau
// at ~2.6 TB/s (~4.3 B/cyc/CU = ~64 miss-slots x 64 B / ~900 cy). Copy
// kernels hit 10 B/cyc/CU with full-wave 64-lane dwordx4 1024 B spans (one
// miss-slot tracks the whole span). This version makes EVERY read instruction
// exactly that shape: block owns [85 ch x 256 sp]; channel-run = 256 floats
// = 64 float4s = ONE full-wave dwordx4 instruction per (wave, channel).
// Thread t holds channels {t>>6 + 8k} at fixed f4-offset q = t&63 (44 data
// VGPRs). Transpose goes through LDS in 4 chunks of [64 sp x 85 ch]
// (21.8 KB), draining with the proven fully-contiguous NT float4 store run.
// Transforms applied in registers at load (wave-uniform: only waves 0-4, k=0).

typedef float nat_float4 __attribute__((ext_vector_type(4)));

#define NSPAT   2704          // 52*52
#define NCH     85            // 5 + 80 classes
#define NSLAB   96            // 32 batches * 3 anchors
#define SP      256           // spatial floats per block tile
#define NTILE   11            // ceil(2704/256): 10 full + one 144-wide tail
#define TPB     512           // 8 waves
#define CHUNK   64            // spatial rows per LDS transpose pass
#define RUNF4   (NSPAT / 4)   // 676 float4 per channel row
#define SLABF4  (NCH * NSPAT / 4)  // 57460 float4 per slab

__global__ __launch_bounds__(TPB) void yolo_decode_kernel(
    const float* __restrict__ in, float* __restrict__ out) {
  __shared__ __align__(16) float tile[CHUNK * NCH];   // 21760 B -> many blocks/CU

  const int t    = threadIdx.x;
  const int w    = t >> 6;                 // wave 0..7
  const int q    = t & 63;                 // f4 offset within channel-run (== lane)
  const int slab = blockIdx.x / NTILE;     // b*3 + a
  const int tt   = blockIdx.x - slab * NTILE;
  const int a    = slab % 3;               // ANCHOR_MASK = [0,1,2]

  const float aw = (a == 0) ? 10.0f : (a == 1) ? 16.0f : 33.0f;
  const float ah = (a == 0) ? 13.0f : (a == 1) ? 30.0f : 23.0f;

  const int s0   = tt * SP;                // 0,256,...,2560
  const int rem  = NSPAT - s0;             // 256 normally, 144 for tail tile
  const int span = (rem < SP) ? rem : SP;  // floats of spatial this block owns
  const int qmax = span >> 2;              // 64 (full) or 36 (tail)
  const bool qok = (q < qmax);

  // ---- Phase 1: register-stage [85ch x span]; every load = 1024 B full-wave span ----
  nat_float4 v[11];
  const nat_float4* src = (const nat_float4*)in
      + (long)slab * SLABF4 + (long)w * RUNF4 + (s0 >> 2) + q;
  if (qok) {
    #pragma unroll
    for (int k = 0; k < 11; ++k) {
      const int c = w + 8 * k;             // wave w owns channels w, w+8, ..., <85
      if (c < NCH) v[k] = src[8 * k * RUNF4];
    }
  }

  // ---- Phase 2: transform in registers. c<5 lives only in v[0] of waves 0..4 ----
  if (qok && w < 5) {
    #pragma unroll
    for (int j = 0; j < 4; ++j) {
      const int sg = s0 + 4 * q + j;       // global spatial: h*52 + w
      float x = v[0][j];
      if (w == 0)      x = 1.0f / (1.0f + __expf(-x)) + (float)(sg % 52);
      else if (w == 1) x = 1.0f / (1.0f + __expf(-x)) + (float)(sg / 52);
      else if (w == 2) x = __expf(x * (1.0f / 416.0f)) * aw;
      else if (w == 3) x = __expf(x * (1.0f / 416.0f)) * ah;
      else             x = 1.0f / (1.0f + __expf(-x));
      v[0][j] = x;
    }
  }

  // ---- Phase 3: transpose via LDS in chunks of 64 spatial rows ----
  const int npass = (span + CHUNK - 1) / CHUNK;   // 4 (full) or 3 (tail)
  for (int p = 0; p < npass; ++p) {
    // stage: threads whose q falls in this chunk's window write ALL their f4s.
    // 16 active lanes/wave, addr stride 340 dw -> 16 lanes on 8 banks = 2-way (free)
    if (qok && (q >> 4) == p) {
      const int sl = (q & 15) << 2;        // local row base 0..60
      #pragma unroll
      for (int k = 0; k < 11; ++k) {
        const int c = w + 8 * k;
        if (c < NCH) {
          tile[(sl + 0) * NCH + c] = v[k].x;
          tile[(sl + 1) * NCH + c] = v[k].y;
          tile[(sl + 2) * NCH + c] = v[k].z;
          tile[(sl + 3) * NCH + c] = v[k].w;
        }
      }
    }
    __syncthreads();

    // drain: one contiguous NT float4 store run (LDS reads stride-1, 2-way free)
    int rows = rem - p * CHUNK;
    if (rows > CHUNK) rows = CHUNK;
    const int nf4 = rows * NCH / 4;        // 1360 full chunk, 340 tail chunk
    const nat_float4* s4 = (const nat_float4*)tile;
    nat_float4* dst = (nat_float4*)out
        + (long)slab * SLABF4 + (long)(s0 + p * CHUNK) * NCH / 4;
    for (int j = t; j < nf4; j += TPB)
      __builtin_nontemporal_store(s4[j], dst + j);
    __syncthreads();
  }
}

extern "C" void kernel_launch(void* const* d_in, const int* in_sizes, int n_in,
                              void* d_out, int out_size, void* d_ws, size_t ws_size,
                              hipStream_t stream) {
  const float* in = (const float*)d_in[0];
  float* out = (float*)d_out;
  yolo_decode_kernel<<<NSLAB * NTILE, TPB, 0, stream>>>(in, out);
}

// Round 2
// 159.942 us; speedup vs baseline: 1.0012x; 1.0012x over previous
//
#include <hip/hip_runtime.h>
#include <math.h>

// YOLO box decode: (32, 3*85, 52, 52) -> (32*3*52*52, 85)
// R11: CACHED (non-NT) STORES. R10 proved the plateau (~2.5 TB/s) is
// insensitive to read-instruction shape (full-wave 1024 B dwordx4 spans),
// occupancy (27% vs 54%), and block structure (R2-R9). The one policy never
// varied: ALL prior versions NT-store the output, and WRITE_SIZE == 87 MB
// (full output to HBM every iter) while FETCH == 46 MB < 88 MB input shows
// the MALL absorbs reads but the NT hint makes writes no-allocate. Working
// set (88 in + 88 out = 176 MB) fits the 256 MB Infinity Cache: with cached
// stores the steady-state iteration should run largely out of L3.
// ONLY change vs R10: __builtin_nontemporal_store -> plain store.

typedef float nat_float4 __attribute__((ext_vector_type(4)));

#define NSPAT   2704          // 52*52
#define NCH     85            // 5 + 80 classes
#define NSLAB   96            // 32 batches * 3 anchors
#define SP      256           // spatial floats per block tile
#define NTILE   11            // ceil(2704/256): 10 full + one 144-wide tail
#define TPB     512           // 8 waves
#define CHUNK   64            // spatial rows per LDS transpose pass
#define RUNF4   (NSPAT / 4)   // 676 float4 per channel row
#define SLABF4  (NCH * NSPAT / 4)  // 57460 float4 per slab

__global__ __launch_bounds__(TPB) void yolo_decode_kernel(
    const float* __restrict__ in, float* __restrict__ out) {
  __shared__ __align__(16) float tile[CHUNK * NCH];   // 21760 B -> many blocks/CU

  const int t    = threadIdx.x;
  const int w    = t >> 6;                 // wave 0..7
  const int q    = t & 63;                 // f4 offset within channel-run (== lane)
  const int slab = blockIdx.x / NTILE;     // b*3 + a
  const int tt   = blockIdx.x - slab * NTILE;
  const int a    = slab % 3;               // ANCHOR_MASK = [0,1,2]

  const float aw = (a == 0) ? 10.0f : (a == 1) ? 16.0f : 33.0f;
  const float ah = (a == 0) ? 13.0f : (a == 1) ? 30.0f : 23.0f;

  const int s0   = tt * SP;                // 0,256,...,2560
  const int rem  = NSPAT - s0;             // 256 normally, 144 for tail tile
  const int span = (rem < SP) ? rem : SP;  // floats of spatial this block owns
  const int qmax = span >> 2;              // 64 (full) or 36 (tail)
  const bool qok = (q < qmax);

  // ---- Phase 1: register-stage [85ch x span]; every load = 1024 B full-wave span ----
  nat_float4 v[11];
  const nat_float4* src = (const nat_float4*)in
      + (long)slab * SLABF4 + (long)w * RUNF4 + (s0 >> 2) + q;
  if (qok) {
    #pragma unroll
    for (int k = 0; k < 11; ++k) {
      const int c = w + 8 * k;             // wave w owns channels w, w+8, ..., <85
      if (c < NCH) v[k] = src[8 * k * RUNF4];
    }
  }

  // ---- Phase 2: transform in registers. c<5 lives only in v[0] of waves 0..4 ----
  if (qok && w < 5) {
    #pragma unroll
    for (int j = 0; j < 4; ++j) {
      const int sg = s0 + 4 * q + j;       // global spatial: h*52 + w
      float x = v[0][j];
      if (w == 0)      x = 1.0f / (1.0f + __expf(-x)) + (float)(sg % 52);
      else if (w == 1) x = 1.0f / (1.0f + __expf(-x)) + (float)(sg / 52);
      else if (w == 2) x = __expf(x * (1.0f / 416.0f)) * aw;
      else if (w == 3) x = __expf(x * (1.0f / 416.0f)) * ah;
      else             x = 1.0f / (1.0f + __expf(-x));
      v[0][j] = x;
    }
  }

  // ---- Phase 3: transpose via LDS in chunks of 64 spatial rows ----
  const int npass = (span + CHUNK - 1) / CHUNK;   // 4 (full) or 3 (tail)
  for (int p = 0; p < npass; ++p) {
    // stage: threads whose q falls in this chunk's window write ALL their f4s.
    // 16 active lanes/wave, addr stride 340 dw -> 16 lanes on 8 banks = 2-way (free)
    if (qok && (q >> 4) == p) {
      const int sl = (q & 15) << 2;        // local row base 0..60
      #pragma unroll
      for (int k = 0; k < 11; ++k) {
        const int c = w + 8 * k;
        if (c < NCH) {
          tile[(sl + 0) * NCH + c] = v[k].x;
          tile[(sl + 1) * NCH + c] = v[k].y;
          tile[(sl + 2) * NCH + c] = v[k].z;
          tile[(sl + 3) * NCH + c] = v[k].w;
        }
      }
    }
    __syncthreads();

    // drain: one contiguous CACHED float4 store run (LDS reads stride-1, 2-way free)
    int rows = rem - p * CHUNK;
    if (rows > CHUNK) rows = CHUNK;
    const int nf4 = rows * NCH / 4;        // 1360 full chunk, 340 tail chunk
    const nat_float4* s4 = (const nat_float4*)tile;
    nat_float4* dst = (nat_float4*)out
        + (long)slab * SLABF4 + (long)(s0 + p * CHUNK) * NCH / 4;
    for (int j = t; j < nf4; j += TPB)
      dst[j] = s4[j];                      // R11: cached store (was NT)
    __syncthreads();
  }
}

extern "C" void kernel_launch(void* const* d_in, const int* in_sizes, int n_in,
                              void* d_out, int out_size, void* d_ws, size_t ws_size,
                              hipStream_t stream) {
  const float* in = (const float*)d_in[0];
  float* out = (float*)d_out;
  yolo_decode_kernel<<<NSLAB * NTILE, TPB, 0, stream>>>(in, out);
}